// Round 8
// baseline (847.229 us; speedup 1.0000x reference)
//
#include <hip/hip_runtime.h>
#include <hip/hip_bf16.h>
#include <stdint.h>

// GNN_758: stacked RelGraphConv x2.  N=50000, E=1.6M, D=128, R=20.
// agg[dst] = sum_r (sum_{e in rel r -> dst} h[src]) @ W[r]; self-loop = rel 20.
// R8: phase 1 = flat per-(group,chunk) edge stream (edges cell-sorted, rl
// embedded in edge word), register accumulate, flush-on-rl-change with plain
// ds_write (each cell owned by one group; zero atomics). 2-deep load pipeline.
// Preprocessing: scatter increments cofs in place (cursor array dropped).

#define NN 50000
#define NE 1600000
#define DIM 128
#define NREL 20
#define NRELP 21
#define TILE 16
#define NTILE (NN / TILE)          // 3125
#define CELLS (NN * 32)            // dst*32 + chunk*8 + rl (rl 0..4 used)
#define SCAN_EPB 2048
#define NBLK_A ((CELLS + SCAN_EPB - 1) / SCAN_EPB)   // 782
#define STR_R 130                  // rel slot stride in floats
#define STR_D 781                  // per-dst stride (odd -> clean banks)
#define SPK_CAP 768                // staged edges per block (mean 512)
#define PACKED_ELEMS (2 * NRELP * 4 * 8 * 64 * 8)   // 688128

typedef __attribute__((ext_vector_type(8))) short short8;
typedef __attribute__((ext_vector_type(4))) float f32x4;

__device__ __forceinline__ unsigned short f32_to_bf16_raw(float f) {
  union { float f; unsigned u; } c; c.f = f;
  unsigned u = c.u;
  return (unsigned short)((u + 0x7fffu + ((u >> 16) & 1u)) >> 16);  // RNE
}
__device__ __forceinline__ float bf16_raw_to_f32(unsigned short s) {
  union { unsigned u; float f; } c; c.u = ((unsigned)s) << 16;
  return c.f;
}

// ---------------- fp32 -> bf16 (x4), nontemporal stores ----------------
__global__ void cvt_bf16_kernel(const float* __restrict__ in,
                                unsigned short* __restrict__ out, int n4) {
  int i = blockIdx.x * 256 + threadIdx.x;
  if (i < n4) {
    float4 f = ((const float4*)in)[i];
    unsigned long long p =
        (unsigned long long)f32_to_bf16_raw(f.x)
      | ((unsigned long long)f32_to_bf16_raw(f.y) << 16)
      | ((unsigned long long)f32_to_bf16_raw(f.z) << 32)
      | ((unsigned long long)f32_to_bf16_raw(f.w) << 48);
    __builtin_nontemporal_store(p, (unsigned long long*)out + i);  // clean -> L3
  }
}

// ---------------- pack W (+loop_w as rel 20) into B-fragment order ----------------
// WP flat: ((((l*21 + r)*4 + ks)*8 + nc)*64 + lane)*8 + j  (verified R0/R1)
__global__ void pack_w_kernel(const float* __restrict__ W,
                              const float* __restrict__ loop_w,
                              unsigned short* __restrict__ WP) {
  int idx = blockIdx.x * 256 + threadIdx.x;
  if (idx >= PACKED_ELEMS) return;
  int j = idx & 7;       int t = idx >> 3;
  int lane = t & 63;     t >>= 6;
  int nc = t & 7;        t >>= 3;
  int ks = t & 3;        t >>= 2;
  int r = t % NRELP;     int l = t / NRELP;
  int k = ks * 32 + (lane >> 4) * 8 + j;
  int n = nc * 16 + (lane & 15);
  float v = (r < NREL) ? W[(((size_t)l * NREL + r) * DIM + k) * DIM + n]
                       : loop_w[((size_t)l * DIM + k) * DIM + n];
  WP[idx] = f32_to_bf16_raw(v);
}

// ---------------- global cell sort: hist -> scan(A,B,C) -> scatter ----------------
__global__ void hist_kernel(const int* __restrict__ dst, const int* __restrict__ et,
                            unsigned int* __restrict__ cnt, int n) {
  int i = blockIdx.x * 256 + threadIdx.x;
  if (i < n) {
    int e = et[i];
    atomicAdd(&cnt[dst[i] * 32 + (e / 5) * 8 + (e % 5)], 1u);
  }
}

__global__ void scanA_kernel(const unsigned int* __restrict__ cnt,
                             unsigned int* __restrict__ cofs,
                             unsigned int* __restrict__ btot) {
  __shared__ unsigned int buf[256];
  int tid = threadIdx.x;
  int base = blockIdx.x * SCAN_EPB + tid * 8;
  unsigned int v[8], p[8], s = 0;
#pragma unroll
  for (int j = 0; j < 8; ++j) {
    v[j] = (base + j < CELLS) ? cnt[base + j] : 0u;
    p[j] = s; s += v[j];
  }
  buf[tid] = s;
  __syncthreads();
  for (int d = 1; d < 256; d <<= 1) {
    unsigned int a = (tid >= d) ? buf[tid - d] : 0u;
    __syncthreads();
    buf[tid] += a;
    __syncthreads();
  }
  unsigned int excl = buf[tid] - s;
#pragma unroll
  for (int j = 0; j < 8; ++j)
    if (base + j < CELLS) cofs[base + j] = excl + p[j];
  if (tid == 255) btot[blockIdx.x] = buf[255];
}

__global__ void scanB_kernel(unsigned int* __restrict__ btot) {
  __shared__ unsigned int buf[1024];
  int t = threadIdx.x;
  unsigned int v = (t < NBLK_A) ? btot[t] : 0u;
  buf[t] = v;
  __syncthreads();
  for (int d = 1; d < 1024; d <<= 1) {
    unsigned int a = (t >= d) ? buf[t - d] : 0u;
    __syncthreads();
    buf[t] += a;
    __syncthreads();
  }
  if (t < NBLK_A) btot[t] = buf[t] - v;   // exclusive
}

__global__ void scanC_kernel(const unsigned int* __restrict__ btot,
                             unsigned int* __restrict__ cofs,
                             unsigned int* __restrict__ raw) {
  if (blockIdx.x == 0 && threadIdx.x == 0) raw[0] = 0;   // guard: beg(cell 0)
  int base = blockIdx.x * SCAN_EPB + threadIdx.x * 8;
  unsigned int add = btot[blockIdx.x];
#pragma unroll
  for (int j = 0; j < 8; ++j)
    if (base + j < CELLS) cofs[base + j] += add;
}

// scatter consumes cofs in place: afterwards cofs[c] = end(c), so raw[] (with
// raw[0]=0, raw[c+1]=end(c)) is exactly the begin-offset array rgcn reads.
// payload: src(16b) | rl(3b)<<16
__global__ void scatter_kernel(const int* __restrict__ src, const int* __restrict__ dst,
                               const int* __restrict__ et,
                               unsigned int* __restrict__ cofs,
                               unsigned int* __restrict__ es, int n) {
  int i = blockIdx.x * 256 + threadIdx.x;
  if (i < n) {
    int e = et[i];
    unsigned int pos = atomicAdd(&cofs[dst[i] * 32 + (e / 5) * 8 + (e % 5)], 1u);
    es[pos] = (unsigned int)src[i] | ((unsigned int)(e % 5) << 16);
  }
}

// ---------------- fused RGCN layer ----------------
// 3125 blocks x 256 threads (4 waves). LDS ~55 KB -> 2 blocks/CU.
__global__ __launch_bounds__(256) void rgcn_layer_kernel(
    const unsigned short* __restrict__ hb,    // [N,128] bf16
    const unsigned short* __restrict__ WP,    // packed weights
    const float* __restrict__ bias,           // [128] this layer
    int layer,
    const unsigned int* __restrict__ raw,     // [CELLS+1]: raw[c]=beg(c), raw[c+1]=end(c)
    const unsigned int* __restrict__ esg,     // [E] (src|rl<<16), cell-sorted
    float* __restrict__ outf,                 // fp32 out (layer 1) or null
    unsigned short* __restrict__ outb)        // bf16 out (layer 0) or null
{
  __shared__ __align__(16) float S[TILE][STR_D];   // 49984 B
  __shared__ unsigned int cofs_l[513];             // local cell begin offsets
  __shared__ unsigned int spk[SPK_CAP];            // staged edges

  const int tid  = threadIdx.x;
  const int lane = tid & 63;
  const int w    = tid >> 6;        // wave 0..3
  const int quad = lane >> 4;
  const int m    = lane & 15;
  const int g    = w * 4 + quad;    // 16-lane group id == owned dst_local
  const int dst_base = blockIdx.x * TILE;

  for (int i = tid; i < 513; i += 256) cofs_l[i] = raw[blockIdx.x * 512 + i];
  __syncthreads();
  const int e0 = (int)cofs_l[0];
  const int etot = (int)cofs_l[512] - e0;
  const bool lds_ok = (etot <= SPK_CAP);
  for (int i = tid; i < etot && i < SPK_CAP; i += 256) spk[i] = esg[e0 + i];
  __syncthreads();

  f32x4 acc[8];
#pragma unroll
  for (int nc = 0; nc < 8; ++nc) acc[nc] = (f32x4){0.f, 0.f, 0.f, 0.f};

  for (int c = 0; c < 4; ++c) {
    const int rbase = c * 5;
    const int rc = (c == 3) ? 6 : 5;

    // ---- phase 1: flat stream over group's chunk-c edges; flush on rl change ----
    {
      // group zeros its 5 slots (unflushed cells must read as 0)
      const float4 z4 = {0.f, 0.f, 0.f, 0.f};
#pragma unroll
      for (int rl = 0; rl < 5; ++rl) {
        *(float4*)&S[g][rl * STR_R + m * 8]     = z4;
        *(float4*)&S[g][rl * STR_R + m * 8 + 4] = z4;
      }
      const int sIdx = g * 32 + c * 8;
      int i       = (int)cofs_l[sIdx] - e0;
      const int e = (int)cofs_l[sIdx + 5] - e0;
      float a0 = 0.f, a1 = 0.f, a2 = 0.f, a3 = 0.f;
      float a4 = 0.f, a5 = 0.f, a6 = 0.f, a7 = 0.f;
      int cur = -1;
      unsigned int pkn = 0;
      short8 hvn;
      if (i < e) {
        pkn = lds_ok ? spk[i] : esg[e0 + i];
        hvn = *(const short8*)(hb + (size_t)(pkn & 0xffffu) * DIM + m * 8);
      }
      while (i < e) {
        unsigned int pk = pkn;
        short8 hv = hvn;
        if (i + 1 < e) {                      // 2-deep pipeline
          pkn = lds_ok ? spk[i + 1] : esg[e0 + i + 1];
          hvn = *(const short8*)(hb + (size_t)(pkn & 0xffffu) * DIM + m * 8);
        }
        int rl = (int)(pk >> 16);
        if (rl != cur) {                      // group-uniform condition
          if (cur >= 0) {
            *(float4*)&S[g][cur * STR_R + m * 8]     = (float4){a0, a1, a2, a3};
            *(float4*)&S[g][cur * STR_R + m * 8 + 4] = (float4){a4, a5, a6, a7};
          }
          a0 = a1 = a2 = a3 = a4 = a5 = a6 = a7 = 0.f;
          cur = rl;
        }
        a0 += bf16_raw_to_f32((unsigned short)hv[0]);
        a1 += bf16_raw_to_f32((unsigned short)hv[1]);
        a2 += bf16_raw_to_f32((unsigned short)hv[2]);
        a3 += bf16_raw_to_f32((unsigned short)hv[3]);
        a4 += bf16_raw_to_f32((unsigned short)hv[4]);
        a5 += bf16_raw_to_f32((unsigned short)hv[5]);
        a6 += bf16_raw_to_f32((unsigned short)hv[6]);
        a7 += bf16_raw_to_f32((unsigned short)hv[7]);
        ++i;
      }
      if (cur >= 0) {
        *(float4*)&S[g][cur * STR_R + m * 8]     = (float4){a0, a1, a2, a3};
        *(float4*)&S[g][cur * STR_R + m * 8 + 4] = (float4){a4, a5, a6, a7};
      }
      // self-loop (chunk 3, slot 5): own row, unconditional
      if (c == 3) {
        short8 hv = *(const short8*)(hb + (size_t)(dst_base + g) * DIM + m * 8);
        float4 f0, f1;
        f0.x = bf16_raw_to_f32((unsigned short)hv[0]);
        f0.y = bf16_raw_to_f32((unsigned short)hv[1]);
        f0.z = bf16_raw_to_f32((unsigned short)hv[2]);
        f0.w = bf16_raw_to_f32((unsigned short)hv[3]);
        f1.x = bf16_raw_to_f32((unsigned short)hv[4]);
        f1.y = bf16_raw_to_f32((unsigned short)hv[5]);
        f1.z = bf16_raw_to_f32((unsigned short)hv[6]);
        f1.w = bf16_raw_to_f32((unsigned short)hv[7]);
        *(float4*)&S[g][5 * STR_R + m * 8]     = f0;
        *(float4*)&S[g][5 * STR_R + m * 8 + 4] = f1;
      }
    }
    __syncthreads();

    // ---- phase 2: K-split. wave w owns k in [32w, 32w+32); A reused for 8 nc ----
    for (int rl = 0; rl < rc; ++rl) {
      const int r = rbase + rl;
      const float* ap = &S[m][rl * STR_R + w * 32 + quad * 8];
      float4 f0 = *(const float4*)ap;
      float4 f1 = *(const float4*)(ap + 4);
      short8 a;
      a[0] = (short)f32_to_bf16_raw(f0.x);
      a[1] = (short)f32_to_bf16_raw(f0.y);
      a[2] = (short)f32_to_bf16_raw(f0.z);
      a[3] = (short)f32_to_bf16_raw(f0.w);
      a[4] = (short)f32_to_bf16_raw(f1.x);
      a[5] = (short)f32_to_bf16_raw(f1.y);
      a[6] = (short)f32_to_bf16_raw(f1.z);
      a[7] = (short)f32_to_bf16_raw(f1.w);
      const unsigned short* bp =
          WP + ((((size_t)(layer * NRELP + r) * 4 + w) * 8) * 64 + lane) * 8;
#pragma unroll
      for (int nc = 0; nc < 8; ++nc) {
        short8 b = *(const short8*)(bp + (size_t)nc * 64 * 8);
        acc[nc] = __builtin_amdgcn_mfma_f32_16x16x32_bf16(a, b, acc[nc], 0, 0, 0);
      }
    }
    __syncthreads();
  }

  // cross-wave K-reduction through LDS. red[w][row16][132] (reuse S region)
  float* red = &S[0][0];
#pragma unroll
  for (int nc = 0; nc < 8; ++nc)
#pragma unroll
    for (int i = 0; i < 4; ++i)
      red[w * (16 * 132) + (quad * 4 + i) * 132 + nc * 16 + m] = acc[nc][i];
  __syncthreads();

  {
    int row = tid >> 4, cb = (tid & 15) * 8;
    float4 b0 = *(const float4*)(bias + cb);
    float4 b1 = *(const float4*)(bias + cb + 4);
    float o[8];
#pragma unroll
    for (int j = 0; j < 8; ++j) {
      int col = cb + j;
      o[j] = red[0 * 2112 + row * 132 + col] + red[1 * 2112 + row * 132 + col]
           + red[2 * 2112 + row * 132 + col] + red[3 * 2112 + row * 132 + col];
    }
    o[0] += b0.x; o[1] += b0.y; o[2] += b0.z; o[3] += b0.w;
    o[4] += b1.x; o[5] += b1.y; o[6] += b1.z; o[7] += b1.w;
    if (outb) {
      short8 p;
#pragma unroll
      for (int j = 0; j < 8; ++j) p[j] = (short)f32_to_bf16_raw(o[j]);
      *(short8*)(outb + (size_t)(dst_base + row) * DIM + cb) = p;
    } else {
      float* op = outf + (size_t)(dst_base + row) * DIM + cb;
      *(float4*)op       = (float4){o[0], o[1], o[2], o[3]};
      *(float4*)(op + 4) = (float4){o[4], o[5], o[6], o[7]};
    }
  }
}

// ---------------- launch ----------------
extern "C" void kernel_launch(void* const* d_in, const int* in_sizes, int n_in,
                              void* d_out, int out_size, void* d_ws, size_t ws_size,
                              hipStream_t stream) {
  const float* h0     = (const float*)d_in[0];
  const float* W      = (const float*)d_in[1];
  const float* loop_w = (const float*)d_in[2];
  const float* bias   = (const float*)d_in[3];
  const int* esrc     = (const int*)d_in[4];
  const int* edst     = (const int*)d_in[5];
  const int* etyp     = (const int*)d_in[6];
  float* out = (float*)d_out;

  char* ws = (char*)d_ws;
  size_t off = 0;
  auto alloc = [&](size_t bytes) -> void* {
    void* p = ws + off;
    off = (off + bytes + 255) & ~(size_t)255;
    return p;
  };
  unsigned short* hb0  = (unsigned short*)alloc((size_t)NN * DIM * 2);   // 12.8 MB
  unsigned short* hb1  = (unsigned short*)alloc((size_t)NN * DIM * 2);   // 12.8 MB
  unsigned short* WP   = (unsigned short*)alloc((size_t)PACKED_ELEMS * 2);
  unsigned int*   cnt  = (unsigned int*)alloc((size_t)CELLS * 4);        // 6.4 MB
  unsigned int*   raw  = (unsigned int*)alloc((size_t)(CELLS + 1) * 4);  // 6.4 MB
  unsigned int*   btot = (unsigned int*)alloc((size_t)NBLK_A * 4);
  unsigned int*   es   = (unsigned int*)alloc((size_t)NE * 4);           // 6.4 MB
  unsigned int*   cofs = raw + 1;   // cofs[c] at raw[c+1]; raw[0] = 0 guard

  (void)hipMemsetAsync(cnt, 0, (size_t)CELLS * 4, stream);
  hist_kernel<<<NE / 256, 256, 0, stream>>>(edst, etyp, cnt, NE);
  scanA_kernel<<<NBLK_A, 256, 0, stream>>>(cnt, cofs, btot);
  scanB_kernel<<<1, 1024, 0, stream>>>(btot);
  scanC_kernel<<<NBLK_A, 256, 0, stream>>>(btot, cofs, raw);
  scatter_kernel<<<NE / 256, 256, 0, stream>>>(esrc, edst, etyp, cofs, es, NE);

  pack_w_kernel<<<(PACKED_ELEMS + 255) / 256, 256, 0, stream>>>(W, loop_w, WP);
  cvt_bf16_kernel<<<(NN * DIM / 4 + 255) / 256, 256, 0, stream>>>(h0, hb0, NN * DIM / 4);

  rgcn_layer_kernel<<<NTILE, 256, 0, stream>>>(hb0, WP, bias, 0, raw, es,
                                               nullptr, hb1);
  rgcn_layer_kernel<<<NTILE, 256, 0, stream>>>(hb1, WP, bias + DIM, 1, raw, es,
                                               out, nullptr);
}